// Round 3
// baseline (112.486 us; speedup 1.0000x reference)
//
#include <hip/hip_runtime.h>
#include <math.h>

#define BLK    256
#define PP     4                      // point-PAIRS per thread (8 points)
#define NPTS   4096
#define BATCH  16
#define CCHUNK 256                    // candidates per block
#define NC     (NPTS / CCHUNK)        // 16 candidate chunks
#define PCHUNK (BLK * PP * 2)         // 2048 points per block
#define NPC    (NPTS / PCHUNK)        // 2 point chunks

typedef float f32x2 __attribute__((ext_vector_type(2)));

// ws layout: uint32 min-distance bits per (dir, b, point): 2*16*4096 = 131072
// entries (512 KB), sentinel-initialized to 0x7F7F7F7F (3.39e38) via memset.

__global__ __launch_bounds__(BLK) void chamfer_min_kernel(
    const float* __restrict__ pred, const float* __restrict__ target,
    unsigned int* __restrict__ wsmin)
{
    __shared__ __align__(16) float4 cand[CCHUNK];   // (x, y, z, |t|^2)

    const int cchunk = blockIdx.x;        // 0..NC-1
    const int b      = blockIdx.y >> 1;   // NPC == 2
    const int pc     = blockIdx.y & 1;
    const int dir    = blockIdx.z;        // 0: pred->target, 1: target->pred
    const int t      = threadIdx.x;

    const float* mine  = (dir == 0) ? pred : target;
    const float* other = (dir == 0) ? target : pred;

    // ---- stage candidate chunk into LDS as (x,y,z,tt) ----
    const float* ob = other + ((size_t)b * NPTS + (size_t)cchunk * CCHUNK) * 3;
    for (int j = t; j < CCHUNK; j += BLK) {
        float cx = ob[3 * j + 0];
        float cy = ob[3 * j + 1];
        float cz = ob[3 * j + 2];
        cand[j] = make_float4(cx, cy, cz, fmaf(cz, cz, fmaf(cy, cy, cx * cx)));
    }
    __syncthreads();

    // ---- load 2*PP mine points as float2 pairs: .x <-> point 2k, .y <-> 2k+1
    const int pbase = pc * PCHUNK;
    const float* mb = mine + ((size_t)b * NPTS + pbase) * 3;

    f32x2 nx[PP], ny[PP], nz[PP], pp2[PP], m2[PP];
    #pragma unroll
    for (int k = 0; k < PP; ++k) {
        const int pi0 = (2 * k + 0) * BLK + t;
        const int pi1 = (2 * k + 1) * BLK + t;
        float x0 = mb[3 * pi0 + 0], y0 = mb[3 * pi0 + 1], z0 = mb[3 * pi0 + 2];
        float x1 = mb[3 * pi1 + 0], y1 = mb[3 * pi1 + 1], z1 = mb[3 * pi1 + 2];
        nx[k]  = (f32x2){-2.0f * x0, -2.0f * x1};
        ny[k]  = (f32x2){-2.0f * y0, -2.0f * y1};
        nz[k]  = (f32x2){-2.0f * z0, -2.0f * z1};
        pp2[k] = (f32x2){fmaf(z0, z0, fmaf(y0, y0, x0 * x0)),
                         fmaf(z1, z1, fmaf(y1, y1, x1 * x1))};
        m2[k]  = (f32x2){INFINITY, INFINITY};
    }

    // ---- min over candidate chunk: e = tt - 2 p.t  (3 pk_fma + 1 pk_min / 2 pairs)
    for (int j = 0; j < CCHUNK; j += 4) {
        float4 c0 = cand[j + 0];
        float4 c1 = cand[j + 1];
        float4 c2 = cand[j + 2];
        float4 c3 = cand[j + 3];
        #pragma unroll
        for (int k = 0; k < PP; ++k) {
            f32x2 e0 = __builtin_elementwise_fma(nx[k], (f32x2){c0.x, c0.x},
                       __builtin_elementwise_fma(ny[k], (f32x2){c0.y, c0.y},
                       __builtin_elementwise_fma(nz[k], (f32x2){c0.z, c0.z},
                                                 (f32x2){c0.w, c0.w})));
            f32x2 e1 = __builtin_elementwise_fma(nx[k], (f32x2){c1.x, c1.x},
                       __builtin_elementwise_fma(ny[k], (f32x2){c1.y, c1.y},
                       __builtin_elementwise_fma(nz[k], (f32x2){c1.z, c1.z},
                                                 (f32x2){c1.w, c1.w})));
            f32x2 e2 = __builtin_elementwise_fma(nx[k], (f32x2){c2.x, c2.x},
                       __builtin_elementwise_fma(ny[k], (f32x2){c2.y, c2.y},
                       __builtin_elementwise_fma(nz[k], (f32x2){c2.z, c2.z},
                                                 (f32x2){c2.w, c2.w})));
            f32x2 e3 = __builtin_elementwise_fma(nx[k], (f32x2){c3.x, c3.x},
                       __builtin_elementwise_fma(ny[k], (f32x2){c3.y, c3.y},
                       __builtin_elementwise_fma(nz[k], (f32x2){c3.z, c3.z},
                                                 (f32x2){c3.w, c3.w})));
            f32x2 a = __builtin_elementwise_min(e0, e1);
            f32x2 c = __builtin_elementwise_min(e2, e3);
            m2[k] = __builtin_elementwise_min(m2[k],
                    __builtin_elementwise_min(a, c));
        }
    }

    // ---- combine: d = max(pp + min_e, 0); atomicMin on uint bits ----
    unsigned int* wbase = wsmin + ((size_t)dir * BATCH + b) * NPTS + pbase;
    #pragma unroll
    for (int k = 0; k < PP; ++k) {
        float d0 = fmaxf(pp2[k].x + m2[k].x, 0.0f);
        float d1 = fmaxf(pp2[k].y + m2[k].y, 0.0f);
        atomicMin(&wbase[(2 * k + 0) * BLK + t], __float_as_uint(d0));
        atomicMin(&wbase[(2 * k + 1) * BLK + t], __float_as_uint(d1));
    }
}

// Single-block final reduction: sum all per-point mins, scale, write out[0].
__global__ __launch_bounds__(1024) void chamfer_sum_kernel(
    const unsigned int* __restrict__ wsmin, float* __restrict__ out)
{
    __shared__ float warpsum[16];
    const int total4 = (2 * BATCH * NPTS) / 4;   // 32768 uint4
    const uint4* w4 = (const uint4*)wsmin;

    float s = 0.0f;
    for (int i = threadIdx.x; i < total4; i += 1024) {
        uint4 v = w4[i];
        s += __uint_as_float(v.x) + __uint_as_float(v.y)
           + __uint_as_float(v.z) + __uint_as_float(v.w);
    }

    #pragma unroll
    for (int off = 32; off > 0; off >>= 1)
        s += __shfl_down(s, off, 64);

    const int wid  = threadIdx.x >> 6;
    const int lane = threadIdx.x & 63;
    if (lane == 0) warpsum[wid] = s;
    __syncthreads();

    if (threadIdx.x == 0) {
        float acc = 0.0f;
        #pragma unroll
        for (int w = 0; w < 16; ++w) acc += warpsum[w];
        out[0] = acc * (1.0f / ((float)BATCH * (float)NPTS));
    }
}

extern "C" void kernel_launch(void* const* d_in, const int* in_sizes, int n_in,
                              void* d_out, int out_size, void* d_ws, size_t ws_size,
                              hipStream_t stream) {
    const float* pred   = (const float*)d_in[0];
    const float* target = (const float*)d_in[1];
    float* out = (float*)d_out;
    unsigned int* wsmin = (unsigned int*)d_ws;

    const size_t ws_bytes = (size_t)2 * BATCH * NPTS * sizeof(unsigned int);

    // sentinel: 0x7F7F7F7F == 3.39e38f > any real distance
    hipMemsetAsync(wsmin, 0x7F, ws_bytes, stream);

    dim3 grid1(NC, BATCH * NPC, 2);
    chamfer_min_kernel<<<grid1, BLK, 0, stream>>>(pred, target, wsmin);

    chamfer_sum_kernel<<<1, 1024, 0, stream>>>(wsmin, out);
}